// Round 2
// baseline (618.859 us; speedup 1.0000x reference)
//
#include <hip/hip_runtime.h>
#include <hip/hip_bf16.h>
#include <hip/hip_cooperative_groups.h>
#include <math.h>

namespace cg = cooperative_groups;

// Problem constants (fixed by the reference)
#define NN 8192     // nodes
#define FF 16       // node features
#define HH 64       // hidden
#define GG 256      // graphs
#define LN_EPS 1e-3f
#define KSPLIT 8
#define KC (NN / KSPLIT)   // 1024
#define NBLK 1024          // cooperative grid: 4 blocks/CU x 256 CUs

// acc scratch layout (floats)
#define OFF_G     0
#define OFF_ZMAX  (GG * HH)
#define OFF_ZSUM  (GG * HH + GG)
#define OFF_BARY  (GG * HH + 2 * GG)
#define ACC_TOT   (GG * HH + 2 * GG + 3 * GG)   // 17664 floats

typedef __bf16 bf16x8 __attribute__((ext_vector_type(8)));
typedef float  floatx4 __attribute__((ext_vector_type(4)));

struct Args {
    const float* X; const float* A; const int* I;
    const float* W0; const float* b0; const float* g0; const float* be0;
    const float* W1; const float* b1; const float* g1; const float* be1;
    const float* Wf; const float* bf; const float* Wa; const float* ba;
    const float* Wo; const float* bo;
    float* Cp; __hip_bfloat16* Zt0; __hip_bfloat16* Zt1;
    float* h0; float* h; float* zarr; float* acc; float* out;
};

union SM {
    struct { float Xs[64][17]; } p0;                    // 4.3 KB
    struct { float hs[16][65]; float Ws[64][65]; } p2;  // 20.8 KB
};

// ---------------------------------------------------------------------------
// PZ: zero the atomic-accumulator region (g, zmax, zsum, baryn)
__device__ __forceinline__ void phase_zero(const Args& a, int bid, int t) {
    const int idx = bid * 256 + t;
    if (idx < ACC_TOT) a.acc[idx] = 0.f;
}

// ---------------------------------------------------------------------------
// P0: Zt0 = (X @ W0)^T (bf16 [64][8192]); z = log1p(relu(X[:,0])) + seg-max.
// 1024 blocks = 128 node-tiles x 8 col-groups (8 cols each).
__device__ __forceinline__ void phase0(const Args& a, SM& sm, int bid, int t) {
    const int tile = bid >> 3, cgp = bid & 7;
    const int i0 = tile * 64;
    {   // stage X tile (64x16) -- one float4 per thread, coalesced
        const int r = t >> 2, c = (t & 3) * 4;
        const float4 v = *reinterpret_cast<const float4*>(&a.X[(size_t)(i0 + r) * FF + c]);
        sm.p0.Xs[r][c + 0] = v.x; sm.p0.Xs[r][c + 1] = v.y;
        sm.p0.Xs[r][c + 2] = v.z; sm.p0.Xs[r][c + 3] = v.w;
    }
    __syncthreads();
    const int i = t & 63;
    const int n = cgp * 8 + ((t >> 6) << 1);   // 2 cols per thread
    float s0 = 0.f, s1 = 0.f;
#pragma unroll
    for (int m = 0; m < FF; ++m) {
        const float hv = sm.p0.Xs[i][m];
        const float2 w = *reinterpret_cast<const float2*>(&a.W0[m * HH + n]);
        s0 += hv * w.x; s1 += hv * w.y;
    }
    a.Zt0[(size_t)n * NN + i0 + i]       = __float2bfloat16(s0);  // 128B coalesced
    a.Zt0[(size_t)(n + 1) * NN + i0 + i] = __float2bfloat16(s1);
    if (cgp == 0 && t < 64) {
        const float z = log1pf(fmaxf(sm.p0.Xs[t][0], 0.f));
        a.zarr[i0 + t] = z;
        atomicMax(reinterpret_cast<unsigned int*>(a.acc + OFF_ZMAX) + a.I[i0 + t],
                  __float_as_uint(z));   // z >= 0: uint compare == float compare
    }
}

// ---------------------------------------------------------------------------
// GEMM phase: Cp[kb] = A[:, kslice](fp32->bf16) @ Zt[kslice, :]
// 1024 blocks = 128 rowblocks x 8 ksplit; 4 waves; 64 rows/block.
__device__ __forceinline__ void phase_gemm(const float* __restrict__ A,
                                           const __hip_bfloat16* __restrict__ Zt,
                                           float* __restrict__ Cp, int bid, int tid) {
    const int wave = tid >> 6;
    const int lane = tid & 63;
    const int l16  = lane & 15;
    const int quad = lane >> 4;
    const int rb   = bid & 127;
    const int kb   = bid >> 7;
    const int row0 = rb * 64;
    const int k0   = kb * KC;

    const float* aptr = A + (size_t)(row0 + wave * 16 + l16) * NN + k0 + quad * 8;
    const __hip_bfloat16* bp0 = Zt + (size_t)(0 * 16 + l16) * NN + k0 + quad * 8;
    const __hip_bfloat16* bp1 = Zt + (size_t)(1 * 16 + l16) * NN + k0 + quad * 8;
    const __hip_bfloat16* bp2 = Zt + (size_t)(2 * 16 + l16) * NN + k0 + quad * 8;
    const __hip_bfloat16* bp3 = Zt + (size_t)(3 * 16 + l16) * NN + k0 + quad * 8;

    floatx4 acc0 = {0.f,0.f,0.f,0.f}, acc1 = {0.f,0.f,0.f,0.f};
    floatx4 acc2 = {0.f,0.f,0.f,0.f}, acc3 = {0.f,0.f,0.f,0.f};

#pragma unroll 4
    for (int k = 0; k < KC; k += 32) {
        const float4 a0 = *reinterpret_cast<const float4*>(aptr + k);
        const float4 a1 = *reinterpret_cast<const float4*>(aptr + k + 4);
        bf16x8 af;
        af[0] = (__bf16)a0.x; af[1] = (__bf16)a0.y;
        af[2] = (__bf16)a0.z; af[3] = (__bf16)a0.w;
        af[4] = (__bf16)a1.x; af[5] = (__bf16)a1.y;
        af[6] = (__bf16)a1.z; af[7] = (__bf16)a1.w;
        const bf16x8 b0 = *reinterpret_cast<const bf16x8*>(bp0 + k);
        const bf16x8 b1 = *reinterpret_cast<const bf16x8*>(bp1 + k);
        const bf16x8 b2 = *reinterpret_cast<const bf16x8*>(bp2 + k);
        const bf16x8 b3 = *reinterpret_cast<const bf16x8*>(bp3 + k);
        acc0 = __builtin_amdgcn_mfma_f32_16x16x32_bf16(af, b0, acc0, 0, 0, 0);
        acc1 = __builtin_amdgcn_mfma_f32_16x16x32_bf16(af, b1, acc1, 0, 0, 0);
        acc2 = __builtin_amdgcn_mfma_f32_16x16x32_bf16(af, b2, acc2, 0, 0, 0);
        acc3 = __builtin_amdgcn_mfma_f32_16x16x32_bf16(af, b3, acc3, 0, 0, 0);
    }

    // C/D layout: m = quad*4 + reg, n = l16 (HW-verified m89/m91)
    float* cp = Cp + ((size_t)kb * NN + row0 + wave * 16 + quad * 4) * HH + l16;
#pragma unroll
    for (int r = 0; r < 4; ++r) {
        cp[(size_t)r * HH +  0] = acc0[r];
        cp[(size_t)r * HH + 16] = acc1[r];
        cp[(size_t)r * HH + 32] = acc2[r];
        cp[(size_t)r * HH + 48] = acc3[r];
    }
}

// ---------------------------------------------------------------------------
// LN core: reduce 8 Cp slabs + bias + relu + LayerNorm. Returns output float4.
__device__ __forceinline__ float4 ln_core(const Args& a, const float* bias,
                                          const float* gamma, const float* beta,
                                          size_t grow, int c0) {
    float4 acc4 = {0.f, 0.f, 0.f, 0.f};
#pragma unroll
    for (int kb = 0; kb < KSPLIT; ++kb) {
        const float4 v = *reinterpret_cast<const float4*>(
            &a.Cp[((size_t)kb * NN + grow) * HH + c0]);
        acc4.x += v.x; acc4.y += v.y; acc4.z += v.z; acc4.w += v.w;
    }
    const float4 b4 = *reinterpret_cast<const float4*>(&bias[c0]);
    float v[4] = { fmaxf(acc4.x + b4.x, 0.f), fmaxf(acc4.y + b4.y, 0.f),
                   fmaxf(acc4.z + b4.z, 0.f), fmaxf(acc4.w + b4.w, 0.f) };
    float s = 0.f, ss = 0.f;
#pragma unroll
    for (int j = 0; j < 4; ++j) { s += v[j]; ss += v[j] * v[j]; }
#pragma unroll
    for (int m = 1; m < 16; m <<= 1) {
        s  += __shfl_xor(s,  m, 64);
        ss += __shfl_xor(ss, m, 64);
    }
    const float mean = s * (1.f / 64.f);
    const float var  = fmaxf(ss * (1.f / 64.f) - mean * mean, 0.f);
    const float inv  = rsqrtf(var + LN_EPS);
    const float4 g4  = *reinterpret_cast<const float4*>(&gamma[c0]);
    const float4 be4 = *reinterpret_cast<const float4*>(&beta[c0]);
    float4 o;
    o.x = (v[0] - mean) * inv * g4.x + be4.x;
    o.y = (v[1] - mean) * inv * g4.y + be4.y;
    o.z = (v[2] - mean) * inv * g4.z + be4.z;
    o.w = (v[3] - mean) * inv * g4.w + be4.w;
    return o;
}

// ---------------------------------------------------------------------------
// P2: h0 = LN(relu(sum Cp + b0)) ; fused Zt1 = (h0 @ W1)^T for these 16 rows.
// blocks 0..511, 16 rows each.
__device__ __forceinline__ void phase2(const Args& a, SM& sm, int bid, int t) {
    if (bid >= 512) return;
    const int row = t >> 4, c0 = (t & 15) * 4;
    const size_t grow0 = (size_t)bid * 16;
    const size_t grow  = grow0 + row;
    const float4 o = ln_core(a, a.b0, a.g0, a.be0, grow, c0);
    *reinterpret_cast<float4*>(&a.h0[grow * HH + c0]) = o;
    sm.p2.hs[row][c0 + 0] = o.x; sm.p2.hs[row][c0 + 1] = o.y;
    sm.p2.hs[row][c0 + 2] = o.z; sm.p2.hs[row][c0 + 3] = o.w;
#pragma unroll
    for (int p = 0; p < 4; ++p) {   // stage W1 (64x64), coalesced
        const int idx = p * 256 + t;
        const int r = idx >> 4, c = (idx & 15) * 4;
        const float4 w = *reinterpret_cast<const float4*>(&a.W1[(size_t)r * HH + c]);
        sm.p2.Ws[r][c + 0] = w.x; sm.p2.Ws[r][c + 1] = w.y;
        sm.p2.Ws[r][c + 2] = w.z; sm.p2.Ws[r][c + 3] = w.w;
    }
    __syncthreads();
    // hw1: wave rq handles rows rq*4..rq*4+3 (uniform per wave -> LDS broadcast);
    // lane n = t&63 -> Ws[m][n] conflict-free (stride 65).
    const int n = t & 63, rq = t >> 6;
    float s0 = 0.f, s1 = 0.f, s2 = 0.f, s3 = 0.f;
#pragma unroll 8
    for (int m = 0; m < HH; ++m) {
        const float w = sm.p2.Ws[m][n];
        s0 += sm.p2.hs[rq * 4 + 0][m] * w;
        s1 += sm.p2.hs[rq * 4 + 1][m] * w;
        s2 += sm.p2.hs[rq * 4 + 2][m] * w;
        s3 += sm.p2.hs[rq * 4 + 3][m] * w;
    }
    __hip_bfloat16 hb0 = __float2bfloat16(s0), hb1 = __float2bfloat16(s1);
    __hip_bfloat16 hb2 = __float2bfloat16(s2), hb3 = __float2bfloat16(s3);
    ushort4 u;
    u.x = *reinterpret_cast<unsigned short*>(&hb0);
    u.y = *reinterpret_cast<unsigned short*>(&hb1);
    u.z = *reinterpret_cast<unsigned short*>(&hb2);
    u.w = *reinterpret_cast<unsigned short*>(&hb3);
    *reinterpret_cast<ushort4*>(&a.Zt1[(size_t)n * NN + grow0 + rq * 4]) = u;
}

// ---------------------------------------------------------------------------
// P4: h = LN(relu(sum Cp + b1)) + h0 (residual). blocks 0..511.
__device__ __forceinline__ void phase4(const Args& a, int bid, int t) {
    if (bid >= 512) return;
    const int row = t >> 4, c0 = (t & 15) * 4;
    const size_t grow = (size_t)bid * 16 + row;
    float4 o = ln_core(a, a.b1, a.g1, a.be1, grow, c0);
    const float4 r4 = *reinterpret_cast<const float4*>(&a.h0[grow * HH + c0]);
    o.x += r4.x; o.y += r4.y; o.z += r4.z; o.w += r4.w;
    *reinterpret_cast<float4*>(&a.h[grow * HH + c0]) = o;
}

// ---------------------------------------------------------------------------
// P5: feat/attn pool (g atomics) + barycentre accumulation. Wave per node, 2 reps.
__device__ __forceinline__ void phase5(const Args& a, int bid, int t) {
    const int w = t >> 6, l = t & 63;
#pragma unroll
    for (int rep = 0; rep < 2; ++rep) {
        const int node = rep * 4096 + bid * 4 + w;
        const float hvl = a.h[(size_t)node * HH + l];
        float sf = a.bf[l], sa = a.ba[l];
#pragma unroll 8
        for (int m = 0; m < HH; ++m) {
            const float hv = __shfl(hvl, m, 64);   // broadcast h[node][m]
            sf += hv * a.Wf[m * HH + l];
            sa += hv * a.Wa[m * HH + l];
        }
        const float attn = 1.f / (1.f + expf(-sa));
        const int seg = a.I[node];
        atomicAdd(&a.acc[OFF_G + (size_t)seg * HH + l], sf * attn);
        if (l < 4) {
            const float ze = expf(a.zarr[node] - a.acc[OFF_ZMAX + seg]);
            if (l == 0) atomicAdd(&a.acc[OFF_ZSUM + seg], ze);
            else        atomicAdd(&a.acc[OFF_BARY + seg * 3 + (l - 1)],
                                  ze * a.X[(size_t)node * FF + 12 + l]);
        }
    }
}

// ---------------------------------------------------------------------------
// P6: out[gi] = concat(g[gi], baryn[gi]/zsum[gi]) @ Wout + bout. blocks 0..63.
__device__ __forceinline__ void phase6(const Args& a, int bid, int t) {
    if (bid >= 64) return;
    const int w = t >> 6, lane = t & 63;
    const int gi = bid * 4 + w;
    const float vg = a.acc[OFF_G + (size_t)gi * HH + lane];
    const float zs = a.acc[OFF_ZSUM + gi];
    const float invz = (zs > 0.f) ? (1.f / zs) : 0.f;
    const float extra = (lane < 3) ? a.acc[OFF_BARY + gi * 3 + lane] * invz : 0.f;
#pragma unroll
    for (int d = 0; d < 3; ++d) {
        float p = vg * a.Wo[lane * 3 + d];
        if (lane < 3) p += extra * a.Wo[(HH + lane) * 3 + d];
#pragma unroll
        for (int m = 1; m < 64; m <<= 1) p += __shfl_xor(p, m, 64);
        if (lane == 0) a.out[gi * 3 + d] = p + a.bo[d];
    }
}

// ---------------------------------------------------------------------------
// Mega cooperative kernel: one dispatch for the whole pipeline.
__global__ __launch_bounds__(256, 4) void mega(Args a) {
    __shared__ SM sm;
    cg::grid_group grid = cg::this_grid();
    const int bid = blockIdx.x, t = threadIdx.x;
    phase_zero(a, bid, t);                 grid.sync();
    phase0(a, sm, bid, t);                 grid.sync();
    phase_gemm(a.A, a.Zt0, a.Cp, bid, t);  grid.sync();
    phase2(a, sm, bid, t);                 grid.sync();
    phase_gemm(a.A, a.Zt1, a.Cp, bid, t);  grid.sync();
    phase4(a, bid, t);                     grid.sync();
    phase5(a, bid, t);                     grid.sync();
    phase6(a, bid, t);
}

// Fallback path (if cooperative co-residency unavailable): same phases, 8 dispatches.
__global__ __launch_bounds__(256, 4) void k_pz(Args a){ phase_zero(a, blockIdx.x, threadIdx.x); }
__global__ __launch_bounds__(256, 4) void k_p0(Args a){ __shared__ SM sm; phase0(a, sm, blockIdx.x, threadIdx.x); }
__global__ __launch_bounds__(256, 4) void k_pg0(Args a){ phase_gemm(a.A, a.Zt0, a.Cp, blockIdx.x, threadIdx.x); }
__global__ __launch_bounds__(256, 4) void k_p2(Args a){ __shared__ SM sm; phase2(a, sm, blockIdx.x, threadIdx.x); }
__global__ __launch_bounds__(256, 4) void k_pg1(Args a){ phase_gemm(a.A, a.Zt1, a.Cp, blockIdx.x, threadIdx.x); }
__global__ __launch_bounds__(256, 4) void k_p4(Args a){ phase4(a, blockIdx.x, threadIdx.x); }
__global__ __launch_bounds__(256, 4) void k_p5(Args a){ phase5(a, blockIdx.x, threadIdx.x); }
__global__ __launch_bounds__(256, 4) void k_p6(Args a){ phase6(a, blockIdx.x, threadIdx.x); }

// ---------------------------------------------------------------------------
extern "C" void kernel_launch(void* const* d_in, const int* in_sizes, int n_in,
                              void* d_out, int out_size, void* d_ws, size_t ws_size,
                              hipStream_t stream) {
    Args a;
    a.X   = (const float*)d_in[0];
    a.A   = (const float*)d_in[1];
    a.I   = (const int*)d_in[2];
    a.W0  = (const float*)d_in[3];
    a.b0  = (const float*)d_in[4];
    a.g0  = (const float*)d_in[5];
    a.be0 = (const float*)d_in[6];
    a.W1  = (const float*)d_in[7];
    a.b1  = (const float*)d_in[8];
    a.g1  = (const float*)d_in[9];
    a.be1 = (const float*)d_in[10];
    a.Wf  = (const float*)d_in[11];
    a.bf  = (const float*)d_in[12];
    a.Wa  = (const float*)d_in[13];
    a.ba  = (const float*)d_in[14];
    a.Wo  = (const float*)d_in[15];
    a.bo  = (const float*)d_in[16];

    char* ws = (char*)d_ws;
    // [Cp 16MiB][Zt0 1MiB][Zt1 1MiB][h0 2MiB][h 2MiB][zarr 32KiB][acc ~70KB]
    a.Cp   = (float*)ws;
    a.Zt0  = (__hip_bfloat16*)(ws + (16u << 20));
    a.Zt1  = (__hip_bfloat16*)(ws + (17u << 20));
    a.h0   = (float*)(ws + (18u << 20));
    a.h    = (float*)(ws + (20u << 20));
    a.zarr = (float*)(ws + (22u << 20));
    a.acc  = (float*)(ws + (22u << 20) + (64u << 10));
    a.out  = (float*)d_out;

    static int coop = -1;
    if (coop < 0) {   // one-time co-residency check (host queries; graph-capture safe)
        int occ = 0, ncu = 0, dev = 0;
        hipGetDevice(&dev);
        hipOccupancyMaxActiveBlocksPerMultiprocessor(&occ, mega, 256, 0);
        hipDeviceGetAttribute(&ncu, hipDeviceAttributeMultiprocessorCount, dev);
        coop = (occ * ncu >= NBLK) ? 1 : 0;
    }

    bool launched = false;
    if (coop) {
        void* kargs[] = { (void*)&a };
        hipError_t err = hipLaunchCooperativeKernel(
            reinterpret_cast<const void*>(mega), dim3(NBLK), dim3(256), kargs, 0, stream);
        launched = (err == hipSuccess);
    }
    if (!launched) {
        k_pz <<<NBLK, 256, 0, stream>>>(a);
        k_p0 <<<NBLK, 256, 0, stream>>>(a);
        k_pg0<<<NBLK, 256, 0, stream>>>(a);
        k_p2 <<<512,  256, 0, stream>>>(a);
        k_pg1<<<NBLK, 256, 0, stream>>>(a);
        k_p4 <<<512,  256, 0, stream>>>(a);
        k_p5 <<<NBLK, 256, 0, stream>>>(a);
        k_p6 <<<64,   256, 0, stream>>>(a);
    }
}